// Round 7
// baseline (210.085 us; speedup 1.0000x reference)
//
#include <hip/hip_runtime.h>

#define N_NODES 100000
#define N_EDGES 300000
#define N_GRAPHS 4000
#define CAP 32

typedef float f32x4 __attribute__((ext_vector_type(4)));
typedef float f32x16 __attribute__((ext_vector_type(16)));
typedef __bf16 bf16x8 __attribute__((ext_vector_type(8)));
typedef __bf16 bf16x4 __attribute__((ext_vector_type(4)));
typedef __bf16 bf16x2 __attribute__((ext_vector_type(2)));
typedef _Float16 f16x8 __attribute__((ext_vector_type(8)));

// ---------------- workspace layout (float offsets) ----------------
static const size_t OFF_XA    = 0;                                   // N*16
static const size_t OFF_AD4   = OFF_XA + (size_t)N_NODES * 16;       // N*4
static const size_t OFF_P2B   = OFF_AD4 + (size_t)N_NODES * 4;       // N*128 bf16
static const size_t OFF_ASAD2 = OFF_P2B + (size_t)N_NODES * 64;      // N*2
static const size_t OFF_W2T   = OFF_ASAD2 + (size_t)N_NODES * 2;     // 65536 bf16 = [c][j]
static const size_t OFF_W1B   = OFF_W2T + 32768;                     // 8192 f16 (pi-permuted, b1 in k=9)
static const size_t OFF_GST   = OFF_W1B + 4096;                      // gstart[4001]
static const size_t OFF_INT   = OFF_GST + 4096;                      // deg[N], bucket[N*CAP]

// k_pre block partition (256 threads each); deg zeroed by memset before launch
#define PRE_NODE_END 391   // ceil(100000/256)
#define PRE_PACKB_END 455  // +64: W2^T bf16 pack [128][512]
#define PRE_W1B_END 487    // +32: W1^T f16 pack [512][16], pi-permuted, b1 folded at k=9
#define PRE_GST_END 503    // +16: gstart
#define PRE_BKT_END 1675   // +1172: edge bucketing

__device__ __forceinline__ float lrelu(float x) { return x < 0.f ? 0.2f * x : x; }
__device__ __forceinline__ float elu(float x)   { return x > 0.f ? x : __expf(x) - 1.f; }

// pi: involution on j within each 16-block: [4..7] <-> [8..11].
// Makes stage-A's 32x32 D-register layout coincide with phase-2's B-fragment
// (k = qh*8+e) so H2 never leaves registers.
__device__ __forceinline__ int pi_j(int j) {
    int l = j & 15;
    int d = (l >= 4 && l < 8) ? 4 : (l >= 8 && l < 12) ? -4 : 0;
    return j + d;
}

// Fat pre-kernel: node pack || W2^T pack || W1^T(pi)+b1 pack || gstart || edge bucket
__global__ __launch_bounds__(256) void k_pre(
    const float* __restrict__ x, const float* __restrict__ W1,
    const float* __restrict__ a_src1, const float* __restrict__ a_dst1,
    const float* __restrict__ W2, const float* __restrict__ b1,
    const int* __restrict__ batch, const int* __restrict__ ei,
    float* __restrict__ xa, float* __restrict__ ad4,
    __bf16* __restrict__ w2t, _Float16* __restrict__ w1b,
    int* __restrict__ deg, int* __restrict__ bucket, int* __restrict__ gstart) {
    int b = blockIdx.x, tid = threadIdx.x;
    if (b < PRE_NODE_END) {
        __shared__ float wf[72];
        if (tid < 72) {
            int isd = tid / 36, r = tid % 36, k = r / 4, h = r % 4;
            const float* a = isd ? a_dst1 : a_src1;
            float s = 0.f;
            for (int c = 0; c < 128; c++) s += W1[k * 512 + h * 128 + c] * a[h * 128 + c];
            wf[tid] = s;
        }
        __syncthreads();
        int n = b * 256 + tid;
        if (n >= N_NODES) return;
        float xv[9];
#pragma unroll
        for (int k = 0; k < 9; k++) xv[k] = x[n * 9 + k];
        float as[4], ad[4];
#pragma unroll
        for (int h = 0; h < 4; h++) {
            float s = 0.f, d = 0.f;
#pragma unroll
            for (int k = 0; k < 9; k++) {
                s += xv[k] * wf[k * 4 + h];
                d += xv[k] * wf[36 + k * 4 + h];
            }
            as[h] = s; ad[h] = d;
        }
        f32x4* xp = (f32x4*)(xa + (size_t)n * 16);
        xp[0] = (f32x4){xv[0], xv[1], xv[2], xv[3]};
        xp[1] = (f32x4){xv[4], xv[5], xv[6], xv[7]};
        xp[2] = (f32x4){xv[8], as[0], as[1], as[2]};
        xp[3] = (f32x4){as[3], 0.f, 0.f, 0.f};
        *(f32x4*)(ad4 + (size_t)n * 4) = (f32x4){ad[0], ad[1], ad[2], ad[3]};
    } else if (b < PRE_PACKB_END) {
        int t = (b - PRE_NODE_END) * 256 + tid;
#pragma unroll
        for (int m = 0; m < 4; m++) {
            int idx = t * 4 + m;                 // c*512 + j
            int c = idx >> 9, j = idx & 511;
            w2t[idx] = (__bf16)W2[(size_t)j * 128 + c];
        }
    } else if (b < PRE_W1B_END) {
        int t = (b - PRE_PACKB_END) * 256 + tid;   // 0..8191 = j*16+k
        int j = t >> 4, k = t & 15;
        int jp = pi_j(j);
        float v = (k < 9) ? W1[(size_t)k * 512 + jp] : (k == 9) ? b1[jp] : 0.f;
        w1b[t] = (_Float16)v;
    } else if (b < PRE_GST_END) {
        int g = (b - PRE_W1B_END) * 256 + tid;
        if (g > N_GRAPHS) return;
        int lo = 0, hi = N_NODES;
        while (lo < hi) { int mid = (lo + hi) >> 1; if (batch[mid] < g) lo = mid + 1; else hi = mid; }
        gstart[g] = lo;
    } else {
        int e = (b - PRE_GST_END) * 256 + tid;
        if (e >= N_EDGES) return;
        int s = ei[e], d = ei[N_EDGES + e];
        int slot = atomicAdd(&deg[d], 1);
        if (slot < CAP) bucket[d * CAP + slot] = s;
    }
}

// Fused mega-kernel, TWO barriers, all-register H2 dataflow:
//   phase 0: gather (4 slots x 2 head-pairs/node) -> AgF f16 [4][64][24],
//            with Ag[k=9] = 1.0 (bias lane against w1b's k=9 = b1 row)
//   barrier
//   per wave (ct 0..3, nt 0..1), NO further sync: for each j-block (16):
//     av = W1^T(pi) frag -> f16 MFMA (D[j, node]) -> elu (bias already in)
//     -> bf16 pack: B-frag element e = reg 8*sp+e (pi makes this an identity)
//     -> 2x { afr = W2^T frag, acc = mfma_32x32x16_bf16(afr, bfr, acc) }
//   epilogue: p2b stores from acc^T layout; asad2 partials -> red LDS
//   barrier -> 8-slot reduce -> asad2
__global__ __launch_bounds__(512, 4) void k_gemm(
    const float* __restrict__ xa, const float* __restrict__ ad4,
    const int* __restrict__ deg, const int* __restrict__ bucket,
    const _Float16* __restrict__ w1b, const __bf16* __restrict__ w2t,
    const float* __restrict__ a_src2, const float* __restrict__ a_dst2,
    __bf16* __restrict__ p2b, float* __restrict__ asad2) {
    __shared__ _Float16 AgF[4 * 64 * 24]; // 12 KB, [head][node][24] (k 0..15 used)
    __shared__ float red[64 * 34];        // 8.5 KB, [node][2 sc x 17] (slots 0..7 used)
    const int tid = threadIdx.x;
    const int lane = tid & 63;
    const int w = tid >> 6;
    const int l31 = lane & 31;
    const int qh = lane >> 5;
    const int ct = w >> 1;               // c-tile 0..3
    const int nt = w & 1;                // node-tile 0..1
    const int m0 = blockIdx.x * 64;

    // ---- phase 0: 4 slots x 2 head-pairs per node ----
    {
        const int r = tid >> 3, sub = tid & 7;
        const int hp = sub & 1;
        const int slot = sub >> 1;
        const int n = m0 + r;
        float acc0[2][9] = {};
        float z[2] = {};
        const bool valid = (n < N_NODES);
        if (valid) {
            const float2 adv = *(const float2*)(ad4 + (size_t)n * 4 + hp * 2);
            int dg = deg[n];
            if (dg > CAP) dg = CAP;
#define GATHER1(SRC) do {                                                    \
            const f32x4* xp_ = (const f32x4*)(xa + (size_t)(SRC) * 16);      \
            f32x4 v0 = xp_[0], v1 = xp_[1], v2 = xp_[2], v3 = xp_[3];        \
            float as0 = hp ? v2.w : v2.y;                                    \
            float as1 = hp ? v3.x : v2.z;                                    \
            float e0 = __expf(lrelu(as0 + adv.x));                           \
            float e1 = __expf(lrelu(as1 + adv.y));                           \
            z[0] += e0; z[1] += e1;                                          \
            float xs[9] = {v0.x, v0.y, v0.z, v0.w, v1.x, v1.y, v1.z, v1.w, v2.x}; \
            _Pragma("unroll")                                                \
            for (int k = 0; k < 9; k++) {                                    \
                acc0[0][k] += e0 * xs[k]; acc0[1][k] += e1 * xs[k];          \
            }                                                                \
        } while (0)
            if (slot == 3) GATHER1(n);
            int j = slot;
            int srcn = (j < dg) ? bucket[n * CAP + j] : -1;
            while (srcn >= 0) {
                int src = srcn;
                j += 4;
                srcn = (j < dg) ? bucket[n * CAP + j] : -1;
                GATHER1(src);
            }
#undef GATHER1
        }
#pragma unroll
        for (int off = 2; off <= 4; off <<= 1) {
#pragma unroll
            for (int h = 0; h < 2; h++) {
                z[h] += __shfl_xor(z[h], off);
#pragma unroll
                for (int k = 0; k < 9; k++) acc0[h][k] += __shfl_xor(acc0[h][k], off);
            }
        }
        if (sub < 2) {
#pragma unroll
            for (int hh = 0; hh < 2; hh++) {
                float inv = valid ? 1.f / z[hh] : 0.f;
                f16x8 p0, p1;
#pragma unroll
                for (int k = 0; k < 8; k++) { p0[k] = (_Float16)(acc0[hh][k] * inv); p1[k] = (_Float16)0.f; }
                p1[0] = (_Float16)(acc0[hh][8] * inv);
                p1[1] = (_Float16)1.f;     // bias lane: pairs with w1b k=9 = b1
                _Float16* dst = AgF + (size_t)((sub * 2 + hh) * 64 + r) * 24;
                *(f16x8*)dst = p0;
                *(f16x8*)(dst + 8) = p1;
            }
        }
    }
    __syncthreads();

    // ---- main loop: all-register two-stage MFMA, no cross-wave sync ----
    f32x16 acc = (f32x16){0.f, 0.f, 0.f, 0.f, 0.f, 0.f, 0.f, 0.f,
                          0.f, 0.f, 0.f, 0.f, 0.f, 0.f, 0.f, 0.f};
    const _Float16* avbase = w1b + (size_t)l31 * 16 + qh * 8;
    const __bf16* w2base = w2t + (size_t)(ct * 32 + l31) * 512 + qh * 8;

    for (int head = 0; head < 4; head++) {
        f16x8 agB = *(const f16x8*)&AgF[(size_t)(head * 64 + nt * 32 + l31) * 24 + qh * 8];
#pragma unroll
        for (int jbl = 0; jbl < 4; jbl++) {
            const int jb = head * 4 + jbl;
            f16x8 av = *(const f16x8*)(avbase + (size_t)jb * 512);   // rows jb*32..+31
            f32x16 cfr = (f32x16){0.f, 0.f, 0.f, 0.f, 0.f, 0.f, 0.f, 0.f,
                                  0.f, 0.f, 0.f, 0.f, 0.f, 0.f, 0.f, 0.f};
            cfr = __builtin_amdgcn_mfma_f32_32x32x16_f16(av, agB, cfr, 0, 0, 0);
            float ve[16];
#pragma unroll
            for (int r = 0; r < 16; r++) ve[r] = elu(cfr[r]);
#pragma unroll
            for (int sp = 0; sp < 2; sp++) {
                bf16x8 bfr;
#pragma unroll
                for (int e = 0; e < 8; e++) bfr[e] = (__bf16)ve[8 * sp + e];
                bf16x8 afr = *(const bf16x8*)(w2base + (size_t)(jb * 32 + sp * 16));
                acc = __builtin_amdgcn_mfma_f32_32x32x16_bf16(afr, bfr, acc, 0, 0, 0);
            }
        }
    }

    // ---- epilogue: acc = P2^T[c = ct*32+Q*8+4qh+m, node = nt*32+l31] ----
    const int node = nt * 32 + l31;
    const bool nvalid = (m0 + node < N_NODES);
    float s = 0.f, d = 0.f;
#pragma unroll
    for (int Q = 0; Q < 4; Q++) {
        f32x4 as2q = *(const f32x4*)(a_src2 + ct * 32 + Q * 8 + qh * 4);
        f32x4 ad2q = *(const f32x4*)(a_dst2 + ct * 32 + Q * 8 + qh * 4);
        bf16x4 pk;
#pragma unroll
        for (int m = 0; m < 4; m++) {
            float v = acc[Q * 4 + m];
            pk[m] = (__bf16)v;
            s += v * as2q[m];
            d += v * ad2q[m];
        }
        if (nvalid)
            *(bf16x4*)(p2b + (size_t)(m0 + node) * 128 + ct * 32 + Q * 8 + qh * 4) = pk;
    }
    red[node * 34 + ct * 2 + qh] = s;
    red[node * 34 + 17 + ct * 2 + qh] = d;
    __syncthreads();
    if (tid < 128) {
        int n2 = tid >> 1, cc = tid & 1;
        float sum = 0.f;
#pragma unroll
        for (int sl = 0; sl < 8; sl++) sum += red[n2 * 34 + cc * 17 + sl];
        if (m0 + n2 < N_NODES) asad2[(size_t)(m0 + n2) * 2 + cc] = sum;
    }
}

// Layer-2 attention + aggregation + elu + graph mean, fused:
// ONE BLOCK (4 waves) PER GRAPH; chunk-4 neighbor MLP gathers; LDS reduction.
__global__ __launch_bounds__(256) void k_agg2pool(
    const __bf16* __restrict__ p2b, const float* __restrict__ asad2,
    const int* __restrict__ deg, const int* __restrict__ bucket,
    const float* __restrict__ b2, const int* __restrict__ gstart,
    float* __restrict__ out) {
    __shared__ float red[4 * 128];
    int g = blockIdx.x;
    int tid = threadIdx.x;
    int wv = __builtin_amdgcn_readfirstlane(tid >> 6);
    int lane = tid & 63;
    int s0n = gstart[g], e0n = gstart[g + 1];
    float b2a = b2[2 * lane], b2b = b2[2 * lane + 1];
    float g0 = 0.f, g1 = 0.f;
    for (int n = s0n + wv; n < e0n; n += 4) {
        float ad = asad2[n * 2 + 1];
        float e = __expf(lrelu(asad2[n * 2] + ad));  // self loop
        float z = e;
        bf16x2 v = ((const bf16x2*)(p2b + (size_t)n * 128))[lane];
        float a0 = e * (float)v.x;
        float a1 = e * (float)v.y;
        int dg = deg[n];
        if (dg > CAP) dg = CAP;
        for (int j = 0; j < dg; j += 4) {
            int s0 = bucket[n * CAP + j];
            int s1 = bucket[n * CAP + min(j + 1, dg - 1)];
            int s2 = bucket[n * CAP + min(j + 2, dg - 1)];
            int s3 = bucket[n * CAP + min(j + 3, dg - 1)];
            float l0 = asad2[s0 * 2], l1 = asad2[s1 * 2];
            float l2 = asad2[s2 * 2], l3 = asad2[s3 * 2];
            bf16x2 w0 = ((const bf16x2*)(p2b + (size_t)s0 * 128))[lane];
            bf16x2 w1 = ((const bf16x2*)(p2b + (size_t)s1 * 128))[lane];
            bf16x2 w2 = ((const bf16x2*)(p2b + (size_t)s2 * 128))[lane];
            bf16x2 w3 = ((const bf16x2*)(p2b + (size_t)s3 * 128))[lane];
            float e0 = __expf(lrelu(l0 + ad));
            float e1 = (j + 1 < dg) ? __expf(lrelu(l1 + ad)) : 0.f;
            float e2 = (j + 2 < dg) ? __expf(lrelu(l2 + ad)) : 0.f;
            float e3 = (j + 3 < dg) ? __expf(lrelu(l3 + ad)) : 0.f;
            z += e0 + e1 + e2 + e3;
            a0 += e0 * (float)w0.x + e1 * (float)w1.x + e2 * (float)w2.x + e3 * (float)w3.x;
            a1 += e0 * (float)w0.y + e1 * (float)w1.y + e2 * (float)w2.y + e3 * (float)w3.y;
        }
        float inv = 1.f / z;
        g0 += elu(a0 * inv + b2a);
        g1 += elu(a1 * inv + b2b);
    }
    red[wv * 128 + 2 * lane] = g0;
    red[wv * 128 + 2 * lane + 1] = g1;
    __syncthreads();
    if (tid < 128) {
        float sum = red[tid] + red[128 + tid] + red[256 + tid] + red[384 + tid];
        int cnt = e0n - s0n;
        out[(size_t)g * 128 + tid] = sum / (float)(cnt > 0 ? cnt : 1);
    }
}

extern "C" void kernel_launch(void* const* d_in, const int* in_sizes, int n_in,
                              void* d_out, int out_size, void* d_ws, size_t ws_size,
                              hipStream_t stream) {
    const float* x       = (const float*)d_in[0];
    const int*   ei      = (const int*)d_in[1];
    const int*   batch   = (const int*)d_in[2];
    const float* W1      = (const float*)d_in[3];
    const float* a_src1  = (const float*)d_in[4];
    const float* a_dst1  = (const float*)d_in[5];
    const float* b1      = (const float*)d_in[6];
    const float* W2      = (const float*)d_in[7];
    const float* a_src2  = (const float*)d_in[8];
    const float* a_dst2  = (const float*)d_in[9];
    const float* b2      = (const float*)d_in[10];
    float* out = (float*)d_out;

    float* wsf   = (float*)d_ws;
    float* xa    = wsf + OFF_XA;
    float* ad4   = wsf + OFF_AD4;
    __bf16* p2b  = (__bf16*)(wsf + OFF_P2B);
    float* asad2 = wsf + OFF_ASAD2;
    __bf16* w2t  = (__bf16*)(wsf + OFF_W2T);
    _Float16* w1b = (_Float16*)(wsf + OFF_W1B);
    int* gstart  = (int*)(wsf + OFF_GST);
    int* wsi    = (int*)(wsf + OFF_INT);
    int* deg    = wsi;
    int* bucket = wsi + N_NODES;

    hipMemsetAsync(deg, 0, N_NODES * sizeof(int), stream);
    k_pre<<<PRE_BKT_END, 256, 0, stream>>>(x, W1, a_src1, a_dst1, W2, b1, batch, ei,
                                           xa, ad4, w2t, w1b, deg, bucket, gstart);
    k_gemm<<<(N_NODES + 63) / 64, 512, 0, stream>>>(xa, ad4, deg, bucket, w1b, w2t,
                                                    a_src2, a_dst2, p2b, asad2);
    k_agg2pool<<<N_GRAPHS, 256, 0, stream>>>(p2b, asad2, deg, bucket, b2, gstart, out);
}